// Round 1
// baseline (746.545 us; speedup 1.0000x reference)
//
#include <hip/hip_runtime.h>
#include <math.h>

#define HH 1024
#define WW 1024
#define NB 32
#define TS 64
#define HALO 15
#define KW 31
#define SW (TS + 2*HALO)   // 94 halo tile width
#define ST 95              // sT LDS stride (pad +1)
#define HS 65              // hrow LDS stride (pad +1: stride 64 would be full-wave bank conflict)

// acc layout (doubles): [0] bce_sum, [1..32] inter[b], [33..64] union[b]

__global__ __launch_bounds__(256) void wloss_main(
    const float* __restrict__ inp, const float* __restrict__ tgt,
    double* __restrict__ acc)
{
  __shared__ float sT[SW * ST];     // 94*95*4 = 35720 B
  __shared__ float hrow[SW * HS];   // 94*65*4 = 24440 B
  __shared__ float red[12];

  const int tid = threadIdx.x;
  const int b  = blockIdx.z;
  const int c0 = blockIdx.x * TS;
  const int r0 = blockIdx.y * TS;
  const float* tb = tgt + (size_t)b * (HH * WW);
  const float* ib = inp + (size_t)b * (HH * WW);

  // ---- load target halo tile (zero-padded) ----
  for (int i = tid; i < SW * SW; i += 256) {
    int r = i / SW, c = i - r * SW;
    int gr = r0 - HALO + r, gc = c0 - HALO + c;
    float v = 0.f;
    if ((unsigned)gr < HH && (unsigned)gc < WW) v = tb[(size_t)gr * WW + gc];
    sT[r * ST + c] = v;
  }
  __syncthreads();

  // ---- horizontal 31-wide sliding sums: 94 rows x 2 half-rows ----
  if (tid < 2 * SW) {
    int r  = tid >> 1;
    int cb = (tid & 1) * 32;
    const float* row = &sT[r * ST];
    float s = 0.f;
    #pragma unroll
    for (int k = 0; k < KW; ++k) s += row[cb + k];
    float* hr = &hrow[r * HS];
    hr[cb] = s;
    #pragma unroll 4
    for (int j = 1; j < 32; ++j) {
      s += row[cb + j + 30] - row[cb + j - 1];
      hr[cb + j] = s;
    }
  }
  __syncthreads();

  // ---- vertical sliding sums fused with loss math: 64 cols x 2 half-cols ----
  float a_bce = 0.f, a_int = 0.f, a_uni = 0.f;
  if (tid < 128) {
    int c  = tid & 63;
    int rb = (tid >> 6) * 32;
    float vs = 0.f;
    #pragma unroll
    for (int k = 0; k < KW; ++k) vs += hrow[(rb + k) * HS + c];
    for (int j = 0; j < 32; ++j) {
      int r = rb + j;
      if (j) vs += hrow[(r + 30) * HS + c] - hrow[(r - 1) * HS + c];
      float t = sT[(HALO + r) * ST + HALO + c];
      float w = fmaf(5.f, fabsf(vs * (1.f / 961.f) - t), 1.f);
      float x = ib[(size_t)(r0 + r) * WW + (c0 + c)];
      float ax  = fabsf(x);
      float e   = __expf(-ax);
      float inv = __fdividef(1.f, 1.f + e);
      float p   = (x >= 0.f) ? inv : e * inv;   // sigmoid(x) from exp(-|x|)
      a_bce += fmaxf(x, 0.f) - x * t + __logf(1.f + e);
      a_int  = fmaf(p * t, w, a_int);
      a_uni  = fmaf(p + t, w, a_uni);
    }
  }

  // ---- block reduction (wave64 shuffles, then 4 wave partials) ----
  #pragma unroll
  for (int off = 32; off > 0; off >>= 1) {
    a_bce += __shfl_down(a_bce, off);
    a_int += __shfl_down(a_int, off);
    a_uni += __shfl_down(a_uni, off);
  }
  int wave = tid >> 6;
  if ((tid & 63) == 0) {
    red[wave * 3 + 0] = a_bce;
    red[wave * 3 + 1] = a_int;
    red[wave * 3 + 2] = a_uni;
  }
  __syncthreads();
  if (tid == 0) {
    float sb = 0.f, si = 0.f, su = 0.f;
    #pragma unroll
    for (int wv = 0; wv < 4; ++wv) {
      sb += red[wv * 3 + 0];
      si += red[wv * 3 + 1];
      su += red[wv * 3 + 2];
    }
    atomicAdd(&acc[0], (double)sb);
    atomicAdd(&acc[1 + b], (double)si);
    atomicAdd(&acc[1 + NB + b], (double)su);
  }
}

__global__ void wloss_final(const double* __restrict__ acc, float* __restrict__ out)
{
  if (threadIdx.x == 0 && blockIdx.x == 0) {
    double bce = acc[0] / ((double)NB * HH * WW);
    double s = 0.0;
    for (int b = 0; b < NB; ++b) {
      double inter = acc[1 + b];
      double uni   = acc[1 + NB + b];
      double wiou  = 1.0 - (inter + 1.0) / (uni - inter + 1.0);
      s += bce + wiou;   // wbce[b,c] == bce exactly (scalar * weit, renormalized)
    }
    out[0] = (float)(s / NB);
  }
}

extern "C" void kernel_launch(void* const* d_in, const int* in_sizes, int n_in,
                              void* d_out, int out_size, void* d_ws, size_t ws_size,
                              hipStream_t stream)
{
  const float* inp = (const float*)d_in[0];
  const float* tgt = (const float*)d_in[1];
  double* acc = (double*)d_ws;

  // d_ws is poisoned 0xAA before every call -> zero the accumulators each time.
  hipMemsetAsync(d_ws, 0, (1 + 2 * NB) * sizeof(double), stream);

  dim3 grid(WW / TS, HH / TS, NB);
  wloss_main<<<grid, 256, 0, stream>>>(inp, tgt, acc);
  wloss_final<<<1, 64, 0, stream>>>(acc, (float*)d_out);
}

// Round 2
// 573.601 us; speedup vs baseline: 1.3015x; 1.3015x over previous
//
#include <hip/hip_runtime.h>
#include <math.h>

#define HH 1024
#define WW 1024
#define NB 32
#define TS 64
#define HROWS 94          // TS + 2*15
#define NTASK (HROWS * 8) // 752 horizontal-sum tasks per tile (8 cols each)

// acc layout (doubles): [0] bce_sum, [1..32] inter[b], [33..64] union[b]

template <bool EDGE>
__device__ __forceinline__ void hsum_phase(const float* __restrict__ tb,
                                           int r0, int c0, float* hrow, int tid)
{
  #pragma unroll
  for (int round = 0; round < 3; ++round) {
    int task = round * 256 + tid;
    if (task < NTASK) {
      int rh = task >> 3;       // 0..93  (hrow row; global row r0-15+rh)
      int cg = task & 7;        // 0..7   (8-output column group)
      int gr = r0 - 15 + rh;
      int cb = c0 - 16 + cg * 8; // col of f[0]; 16B-aligned in interior tiles
      float f[40];
      if (EDGE) {
        if ((unsigned)gr < HH) {
          const float* row = tb + (size_t)gr * WW;
          #pragma unroll
          for (int i = 0; i < 40; ++i) {
            int gc = cb + i;
            f[i] = ((unsigned)gc < WW) ? row[gc] : 0.f;
          }
        } else {
          #pragma unroll
          for (int i = 0; i < 40; ++i) f[i] = 0.f;
        }
      } else {
        const float4* r4 = (const float4*)(tb + (size_t)gr * WW + cb);
        #pragma unroll
        for (int u = 0; u < 10; ++u) {
          float4 q = r4[u];
          f[u * 4 + 0] = q.x; f[u * 4 + 1] = q.y;
          f[u * 4 + 2] = q.z; f[u * 4 + 3] = q.w;
        }
      }
      // s = sum f[1..31]  (window for output j=0), 4-way tree partials
      float a0 = 0.f, a1 = 0.f, a2 = 0.f, a3 = 0.f;
      #pragma unroll
      for (int i = 1; i <= 25; i += 4) {
        a0 += f[i]; a1 += f[i + 1]; a2 += f[i + 2]; a3 += f[i + 3];
      }
      float s = (a0 + a1) + (a2 + a3) + f[29] + f[30] + f[31];
      float out[8];
      out[0] = s;
      #pragma unroll
      for (int j = 1; j < 8; ++j) { s += f[j + 31] - f[j]; out[j] = s; }
      float4* dst = (float4*)&hrow[rh * TS + cg * 8];
      dst[0] = make_float4(out[0], out[1], out[2], out[3]);
      dst[1] = make_float4(out[4], out[5], out[6], out[7]);
    }
  }
}

__global__ __launch_bounds__(256) void wloss_main(
    const float* __restrict__ inp, const float* __restrict__ tgt,
    double* __restrict__ acc)
{
  __shared__ float hrow[HROWS * TS]; // 94*64*4 = 24064 B
  __shared__ float red[12];

  const int tid = threadIdx.x;
  const int b  = blockIdx.z;
  const int c0 = blockIdx.x * TS;
  const int r0 = blockIdx.y * TS;
  const float* tb = tgt + (size_t)b * (HH * WW);
  const float* ib = inp + (size_t)b * (HH * WW);

  const bool edge = (blockIdx.x == 0) | (blockIdx.x == gridDim.x - 1) |
                    (blockIdx.y == 0) | (blockIdx.y == gridDim.y - 1);
  if (edge) hsum_phase<true >(tb, r0, c0, hrow, tid);
  else      hsum_phase<false>(tb, r0, c0, hrow, tid);
  __syncthreads();

  // ---- vertical slide fused with loss math: 64 cols x 4 row-groups of 16 ----
  const int c   = tid & 63;
  const int rg  = tid >> 6;
  const int rt0 = rg * 16;

  float vs;
  {
    float a0 = 0.f, a1 = 0.f, a2 = 0.f, a3 = 0.f;
    #pragma unroll
    for (int k = 0; k < 28; k += 4) {
      a0 += hrow[(rt0 + k    ) * TS + c];
      a1 += hrow[(rt0 + k + 1) * TS + c];
      a2 += hrow[(rt0 + k + 2) * TS + c];
      a3 += hrow[(rt0 + k + 3) * TS + c];
    }
    vs = (a0 + a1) + (a2 + a3)
       + hrow[(rt0 + 28) * TS + c] + hrow[(rt0 + 29) * TS + c]
       + hrow[(rt0 + 30) * TS + c];
  }

  float a_bce = 0.f, a_int = 0.f, a_uni = 0.f;
  #pragma unroll 4
  for (int j = 0; j < 16; ++j) {
    if (j) vs += hrow[(rt0 + j + 30) * TS + c] - hrow[(rt0 + j - 1) * TS + c];
    size_t gidx = (size_t)(r0 + rt0 + j) * WW + (c0 + c);
    float t = tb[gidx];
    float x = __builtin_nontemporal_load(&ib[gidx]);
    float w = fmaf(5.f, fabsf(vs * (1.f / 961.f) - t), 1.f);
    float ax  = fabsf(x);
    float e   = __expf(-ax);
    float inv = __fdividef(1.f, 1.f + e);
    float p   = (x >= 0.f) ? inv : e * inv;   // sigmoid from exp(-|x|)
    a_bce += fmaxf(x, 0.f) - x * t + __logf(1.f + e);
    a_int  = fmaf(p * t, w, a_int);
    a_uni  = fmaf(p + t, w, a_uni);
  }

  // ---- block reduction (wave64 shuffles, then 4 wave partials) ----
  #pragma unroll
  for (int off = 32; off > 0; off >>= 1) {
    a_bce += __shfl_down(a_bce, off);
    a_int += __shfl_down(a_int, off);
    a_uni += __shfl_down(a_uni, off);
  }
  int wave = tid >> 6;
  if ((tid & 63) == 0) {
    red[wave * 3 + 0] = a_bce;
    red[wave * 3 + 1] = a_int;
    red[wave * 3 + 2] = a_uni;
  }
  __syncthreads();
  if (tid == 0) {
    float sb = 0.f, si = 0.f, su = 0.f;
    #pragma unroll
    for (int wv = 0; wv < 4; ++wv) {
      sb += red[wv * 3 + 0];
      si += red[wv * 3 + 1];
      su += red[wv * 3 + 2];
    }
    atomicAdd(&acc[0], (double)sb);
    atomicAdd(&acc[1 + b], (double)si);
    atomicAdd(&acc[1 + NB + b], (double)su);
  }
}

__global__ void wloss_final(const double* __restrict__ acc, float* __restrict__ out)
{
  if (threadIdx.x == 0 && blockIdx.x == 0) {
    double bce = acc[0] / ((double)NB * HH * WW);
    double s = 0.0;
    for (int b = 0; b < NB; ++b) {
      double inter = acc[1 + b];
      double uni   = acc[1 + NB + b];
      double wiou  = 1.0 - (inter + 1.0) / (uni - inter + 1.0);
      s += bce + wiou;   // wbce[b,c] == bce exactly (scalar * weit, renormalized)
    }
    out[0] = (float)(s / NB);
  }
}

extern "C" void kernel_launch(void* const* d_in, const int* in_sizes, int n_in,
                              void* d_out, int out_size, void* d_ws, size_t ws_size,
                              hipStream_t stream)
{
  const float* inp = (const float*)d_in[0];
  const float* tgt = (const float*)d_in[1];
  double* acc = (double*)d_ws;

  // d_ws is poisoned 0xAA before every call -> zero the accumulators each time.
  hipMemsetAsync(d_ws, 0, (1 + 2 * NB) * sizeof(double), stream);

  dim3 grid(WW / TS, HH / TS, NB);
  wloss_main<<<grid, 256, 0, stream>>>(inp, tgt, acc);
  wloss_final<<<1, 64, 0, stream>>>(acc, (float*)d_out);
}

// Round 3
// 566.597 us; speedup vs baseline: 1.3176x; 1.0124x over previous
//
#include <hip/hip_runtime.h>
#include <math.h>

#define HH 1024
#define WW 1024
#define NB 32
#define TS 64
#define HROWS 94          // TS + 2*15
#define NTASK (HROWS * 8) // 752 horizontal-sum tasks per tile (8 cols each)
#define TILES_PER_IMG 256 // (1024/64)^2
#define NSLOT (NB * TILES_PER_IMG) // 8192

// ws layout (floats): bceP[8192] | intP[8192] | uniP[8192]  (96 KB, no init needed)

template <bool EDGE>
__device__ __forceinline__ void hsum_phase(const float* __restrict__ tb,
                                           int r0, int c0, float* hrow, int tid)
{
  #pragma unroll
  for (int round = 0; round < 3; ++round) {
    int task = round * 256 + tid;
    if (task < NTASK) {
      int rh = task >> 3;       // 0..93  (hrow row; global row r0-15+rh)
      int cg = task & 7;        // 0..7   (8-output column group)
      int gr = r0 - 15 + rh;
      int cb = c0 - 16 + cg * 8; // col of f[0]; 16B-aligned in interior tiles
      float f[40];
      if (EDGE) {
        if ((unsigned)gr < HH) {
          const float* row = tb + (size_t)gr * WW;
          #pragma unroll
          for (int i = 0; i < 40; ++i) {
            int gc = cb + i;
            f[i] = ((unsigned)gc < WW) ? row[gc] : 0.f;
          }
        } else {
          #pragma unroll
          for (int i = 0; i < 40; ++i) f[i] = 0.f;
        }
      } else {
        const float4* r4 = (const float4*)(tb + (size_t)gr * WW + cb);
        #pragma unroll
        for (int u = 0; u < 10; ++u) {
          float4 q = r4[u];
          f[u * 4 + 0] = q.x; f[u * 4 + 1] = q.y;
          f[u * 4 + 2] = q.z; f[u * 4 + 3] = q.w;
        }
      }
      // s = sum f[1..31]  (window for output j=0), 4-way tree partials
      float a0 = 0.f, a1 = 0.f, a2 = 0.f, a3 = 0.f;
      #pragma unroll
      for (int i = 1; i <= 25; i += 4) {
        a0 += f[i]; a1 += f[i + 1]; a2 += f[i + 2]; a3 += f[i + 3];
      }
      float s = (a0 + a1) + (a2 + a3) + f[29] + f[30] + f[31];
      float out[8];
      out[0] = s;
      #pragma unroll
      for (int j = 1; j < 8; ++j) { s += f[j + 31] - f[j]; out[j] = s; }
      float4* dst = (float4*)&hrow[rh * TS + cg * 8];
      dst[0] = make_float4(out[0], out[1], out[2], out[3]);
      dst[1] = make_float4(out[4], out[5], out[6], out[7]);
    }
  }
}

__global__ __launch_bounds__(256) void wloss_main(
    const float* __restrict__ inp, const float* __restrict__ tgt,
    float* __restrict__ ws)
{
  __shared__ float hrow[HROWS * TS]; // 94*64*4 = 24064 B
  __shared__ float red[12];

  const int tid = threadIdx.x;
  const int b  = blockIdx.z;
  const int c0 = blockIdx.x * TS;
  const int r0 = blockIdx.y * TS;
  const float* tb = tgt + (size_t)b * (HH * WW);
  const float* ib = inp + (size_t)b * (HH * WW);

  const bool edge = (blockIdx.x == 0) | (blockIdx.x == gridDim.x - 1) |
                    (blockIdx.y == 0) | (blockIdx.y == gridDim.y - 1);
  if (edge) hsum_phase<true >(tb, r0, c0, hrow, tid);
  else      hsum_phase<false>(tb, r0, c0, hrow, tid);
  __syncthreads();

  // ---- vertical slide fused with loss math: 64 cols x 4 row-groups of 16 ----
  const int c   = tid & 63;
  const int rg  = tid >> 6;
  const int rt0 = rg * 16;

  float vs;
  {
    float a0 = 0.f, a1 = 0.f, a2 = 0.f, a3 = 0.f;
    #pragma unroll
    for (int k = 0; k < 28; k += 4) {
      a0 += hrow[(rt0 + k    ) * TS + c];
      a1 += hrow[(rt0 + k + 1) * TS + c];
      a2 += hrow[(rt0 + k + 2) * TS + c];
      a3 += hrow[(rt0 + k + 3) * TS + c];
    }
    vs = (a0 + a1) + (a2 + a3)
       + hrow[(rt0 + 28) * TS + c] + hrow[(rt0 + 29) * TS + c]
       + hrow[(rt0 + 30) * TS + c];
  }

  float a_bce = 0.f, a_int = 0.f, a_uni = 0.f;
  #pragma unroll 4
  for (int j = 0; j < 16; ++j) {
    if (j) vs += hrow[(rt0 + j + 30) * TS + c] - hrow[(rt0 + j - 1) * TS + c];
    size_t gidx = (size_t)(r0 + rt0 + j) * WW + (c0 + c);
    float t = tb[gidx];
    float x = __builtin_nontemporal_load(&ib[gidx]);
    float w = fmaf(5.f, fabsf(vs * (1.f / 961.f) - t), 1.f);
    float ax  = fabsf(x);
    float e   = __expf(-ax);
    float inv = __fdividef(1.f, 1.f + e);
    float p   = (x >= 0.f) ? inv : e * inv;   // sigmoid from exp(-|x|)
    a_bce += fmaxf(x, 0.f) - x * t + __logf(1.f + e);
    a_int  = fmaf(p * t, w, a_int);
    a_uni  = fmaf(p + t, w, a_uni);
  }

  // ---- block reduction (wave64 shuffles, then 4 wave partials) ----
  #pragma unroll
  for (int off = 32; off > 0; off >>= 1) {
    a_bce += __shfl_down(a_bce, off);
    a_int += __shfl_down(a_int, off);
    a_uni += __shfl_down(a_uni, off);
  }
  int wave = tid >> 6;
  if ((tid & 63) == 0) {
    red[wave * 3 + 0] = a_bce;
    red[wave * 3 + 1] = a_int;
    red[wave * 3 + 2] = a_uni;
  }
  __syncthreads();
  if (tid == 0) {
    float sb = 0.f, si = 0.f, su = 0.f;
    #pragma unroll
    for (int wv = 0; wv < 4; ++wv) {
      sb += red[wv * 3 + 0];
      si += red[wv * 3 + 1];
      su += red[wv * 3 + 2];
    }
    // contention-free per-block partials (no atomics -> no retire throttling)
    int tile = blockIdx.y * gridDim.x + blockIdx.x;
    int slot = b * TILES_PER_IMG + tile;
    ws[slot]             = sb;
    ws[NSLOT + slot]     = si;
    ws[2 * NSLOT + slot] = su;
  }
}

__global__ __launch_bounds__(1024) void wloss_final(
    const float* __restrict__ ws, float* __restrict__ out)
{
  const float* bceP = ws;
  const float* intP = ws + NSLOT;
  const float* uniP = ws + 2 * NSLOT;
  __shared__ float sB[16];
  __shared__ float sI[NB], sU[NB];

  const int t = threadIdx.x;

  // bce: all 8192 slots, coalesced stride-1024
  float bsum = 0.f;
  #pragma unroll
  for (int k = 0; k < 8; ++k) bsum += bceP[t + k * 1024];

  // per-image inter/union: image = t>>5, 32 lanes x 8 slots each
  const int img = t >> 5, j = t & 31;
  const float* ip = intP + img * TILES_PER_IMG;
  const float* up = uniP + img * TILES_PER_IMG;
  float vi = 0.f, vu = 0.f;
  #pragma unroll
  for (int k = 0; k < 8; ++k) { vi += ip[j + 32 * k]; vu += up[j + 32 * k]; }

  #pragma unroll
  for (int off = 32; off > 0; off >>= 1) bsum += __shfl_down(bsum, off, 64);
  #pragma unroll
  for (int off = 16; off > 0; off >>= 1) {
    vi += __shfl_down(vi, off, 32);
    vu += __shfl_down(vu, off, 32);
  }
  if ((t & 63) == 0) sB[t >> 6] = bsum;
  if (j == 0) { sI[img] = vi; sU[img] = vu; }
  __syncthreads();

  if (t == 0) {
    double bt = 0.0;
    #pragma unroll
    for (int wv = 0; wv < 16; ++wv) bt += (double)sB[wv];
    double bce = bt / ((double)NB * HH * WW);
    double s = 0.0;
    for (int b = 0; b < NB; ++b) {
      double inter = (double)sI[b];
      double uni   = (double)sU[b];
      double wiou  = 1.0 - (inter + 1.0) / (uni - inter + 1.0);
      s += bce + wiou;   // wbce[b,c] == bce exactly (scalar * weit, renormalized)
    }
    out[0] = (float)(s / NB);
  }
}

extern "C" void kernel_launch(void* const* d_in, const int* in_sizes, int n_in,
                              void* d_out, int out_size, void* d_ws, size_t ws_size,
                              hipStream_t stream)
{
  const float* inp = (const float*)d_in[0];
  const float* tgt = (const float*)d_in[1];
  float* ws = (float*)d_ws;   // 3*8192 floats = 96 KB; fully written each launch

  dim3 grid(WW / TS, HH / TS, NB);
  wloss_main<<<grid, 256, 0, stream>>>(inp, tgt, ws);
  wloss_final<<<1, 1024, 0, stream>>>(ws, (float*)d_out);
}

// Round 4
// 349.082 us; speedup vs baseline: 2.1386x; 1.6231x over previous
//
#include <hip/hip_runtime.h>
#include <math.h>

#define HH 1024
#define WW 1024
#define NB 32
#define TS 64
#define IMG (HH * WW)
#define HROWS 94          // TS + 2*15
#define HSTR 68           // hrow LDS stride (68%32=4 spreads phase-1 write banks)
#define NT 4              // tiles per block
#define NBLK 2048         // 8192 tiles / NT
#define TILES_PER_IMG 256
#define NSLOT (NB * TILES_PER_IMG)

// LDS-only barrier: orders ds ops without draining vmcnt -> prefetch loads
// stay in flight across it (the __syncthreads vmcnt(0) drain was the stall).
#define RAW_BARRIER() asm volatile("s_waitcnt lgkmcnt(0)\n\ts_barrier" ::: "memory")

// ws layout (floats): bceP[8192] | intP[8192] | uniP[8192]

// Halo rows of tgt for one 64x64 tile: threads 0..187 = (row 0..93) x (half 0,1),
// each holds 64 floats (16 float4). OOB regions are whole-float4 aligned, so
// clamp-address + mask replaces the old divergent edge path.
__device__ __forceinline__ void load_f(const float* __restrict__ tb,
                                       int r0, int c0, int tid, float fs[64])
{
  if (tid < 188) {
    int rh = tid >> 1, h = tid & 1;
    int gr = r0 - 15 + rh;
    int grc = min(max(gr, 0), HH - 1);
    bool rowOK = ((unsigned)gr < (unsigned)HH);
    int cb = c0 + h * 32 - 16;
    const float* rowp = tb + (size_t)grc * WW;
    #pragma unroll
    for (int u = 0; u < 16; ++u) {
      int colb = cb + 4 * u;
      bool ok = rowOK && (colb >= 0) && (colb <= WW - 4);
      int colc = min(max(colb, 0), WW - 4);
      float4 q = *(const float4*)(rowp + colc);
      fs[4 * u + 0] = ok ? q.x : 0.f;
      fs[4 * u + 1] = ok ? q.y : 0.f;
      fs[4 * u + 2] = ok ? q.z : 0.f;
      fs[4 * u + 3] = ok ? q.w : 0.f;
    }
  }
}

// inp pixels for one tile in phase-2 layout: thread = (col 0..63) x (rowgroup 0..3)
__device__ __forceinline__ void load_x(const float* __restrict__ ib,
                                       int r0, int c0, int tid, float xv[16])
{
  int c = tid & 63, rt0 = (tid >> 6) * 16;
  const float* p = ib + (size_t)(r0 + rt0) * WW + (c0 + c);
  #pragma unroll
  for (int j = 0; j < 16; ++j)
    xv[j] = __builtin_nontemporal_load(&p[(size_t)j * WW]);
}

__global__ __launch_bounds__(256, 3) void wloss_main(
    const float* __restrict__ inp, const float* __restrict__ tgt,
    float* __restrict__ ws)
{
  __shared__ float hrow[HROWS * HSTR]; // 94*68*4 = 25568 B
  __shared__ float red[12];

  const int tid = threadIdx.x;
  const int k = blockIdx.x;            // 0..NBLK-1

  float fs[64];
  float x0[16], x1[16];

  // ---- prologue: prefetch tile 0 ----
  {
    int tile = k;
    int b = tile >> 8, ty = (tile >> 4) & 15, tx = tile & 15;
    load_f(tgt + (size_t)b * IMG, ty * TS, tx * TS, tid, fs);
    load_x(inp + (size_t)b * IMG, ty * TS, tx * TS, tid, x0);
  }

  #pragma unroll
  for (int it = 0; it < NT; ++it) {
    const int tile = k + it * NBLK;
    const int b = tile >> 8, ty = (tile >> 4) & 15, tx = tile & 15;
    const int r0 = ty * TS, c0 = tx * TS;
    const float* tb = tgt + (size_t)b * IMG;
    float* xc = (it & 1) ? x1 : x0;  // folds after full unroll
    float* xn = (it & 1) ? x0 : x1;

    // ---- phase 1: 31-wide horizontal sliding sums from fs -> hrow ----
    if (tid < 188) {
      int rh = tid >> 1, h = tid & 1;
      float a0 = 0.f, a1 = 0.f, a2 = 0.f, a3 = 0.f;
      #pragma unroll
      for (int i = 1; i <= 25; i += 4) {
        a0 += fs[i]; a1 += fs[i + 1]; a2 += fs[i + 2]; a3 += fs[i + 3];
      }
      float s = (a0 + a1) + (a2 + a3) + fs[29] + fs[30] + fs[31];
      float out[32];
      out[0] = s;
      #pragma unroll
      for (int o = 1; o < 32; ++o) { s += fs[o + 31] - fs[o]; out[o] = s; }
      float* hp = &hrow[rh * HSTR + h * 32];
      #pragma unroll
      for (int g = 0; g < 8; ++g)
        *(float4*)&hp[4 * g] =
            make_float4(out[4 * g], out[4 * g + 1], out[4 * g + 2], out[4 * g + 3]);
    }
    RAW_BARRIER();   // hrow write -> read; vmem stays in flight

    // ---- prefetch next tile (overlaps phase 2 compute) ----
    if (it + 1 < NT) {
      int ntile = k + (it + 1) * NBLK;
      int nb = ntile >> 8, nty = (ntile >> 4) & 15, ntx = ntile & 15;
      load_f(tgt + (size_t)nb * IMG, nty * TS, ntx * TS, tid, fs);
      load_x(inp + (size_t)nb * IMG, nty * TS, ntx * TS, tid, xn);
    }

    // ---- phase 2: vertical 31-slide + loss math ----
    const int c = tid & 63;
    const int rt0 = (tid >> 6) * 16;
    float vs;
    {
      float a0 = 0.f, a1 = 0.f, a2 = 0.f, a3 = 0.f;
      #pragma unroll
      for (int kk = 0; kk < 28; kk += 4) {
        a0 += hrow[(rt0 + kk    ) * HSTR + c];
        a1 += hrow[(rt0 + kk + 1) * HSTR + c];
        a2 += hrow[(rt0 + kk + 2) * HSTR + c];
        a3 += hrow[(rt0 + kk + 3) * HSTR + c];
      }
      vs = (a0 + a1) + (a2 + a3)
         + hrow[(rt0 + 28) * HSTR + c] + hrow[(rt0 + 29) * HSTR + c]
         + hrow[(rt0 + 30) * HSTR + c];
    }

    float a_bce = 0.f, a_int = 0.f, a_uni = 0.f;
    #pragma unroll 4
    for (int j = 0; j < 16; ++j) {
      if (j) vs += hrow[(rt0 + j + 30) * HSTR + c] - hrow[(rt0 + j - 1) * HSTR + c];
      float t = tb[(size_t)(r0 + rt0 + j) * WW + (c0 + c)];  // L1/L2-hot (phase-1 touched)
      float x = xc[j];
      float w = fmaf(5.f, fabsf(vs * (1.f / 961.f) - t), 1.f);
      float ax  = fabsf(x);
      float e   = __expf(-ax);
      float inv = __fdividef(1.f, 1.f + e);
      float p   = (x >= 0.f) ? inv : e * inv;   // sigmoid from exp(-|x|)
      a_bce += fmaxf(x, 0.f) - x * t + __logf(1.f + e);
      a_int  = fmaf(p * t, w, a_int);
      a_uni  = fmaf(p + t, w, a_uni);
    }

    // ---- block reduction ----
    #pragma unroll
    for (int off = 32; off > 0; off >>= 1) {
      a_bce += __shfl_down(a_bce, off);
      a_int += __shfl_down(a_int, off);
      a_uni += __shfl_down(a_uni, off);
    }
    int wave = tid >> 6;
    if ((tid & 63) == 0) {
      red[wave * 3 + 0] = a_bce;
      red[wave * 3 + 1] = a_int;
      red[wave * 3 + 2] = a_uni;
    }
    RAW_BARRIER();   // red write -> read; also fences hrow reuse next iter
    if (tid == 0) {
      float sb = 0.f, si = 0.f, su = 0.f;
      #pragma unroll
      for (int wv = 0; wv < 4; ++wv) {
        sb += red[wv * 3 + 0];
        si += red[wv * 3 + 1];
        su += red[wv * 3 + 2];
      }
      ws[tile]             = sb;
      ws[NSLOT + tile]     = si;
      ws[2 * NSLOT + tile] = su;
    }
  }
}

__global__ __launch_bounds__(1024) void wloss_final(
    const float* __restrict__ ws, float* __restrict__ out)
{
  const float* bceP = ws;
  const float* intP = ws + NSLOT;
  const float* uniP = ws + 2 * NSLOT;
  __shared__ float sB[16];
  __shared__ float sI[NB], sU[NB];

  const int t = threadIdx.x;

  float bsum = 0.f;
  #pragma unroll
  for (int kk = 0; kk < 8; ++kk) bsum += bceP[t + kk * 1024];

  const int img = t >> 5, j = t & 31;
  const float* ip = intP + img * TILES_PER_IMG;
  const float* up = uniP + img * TILES_PER_IMG;
  float vi = 0.f, vu = 0.f;
  #pragma unroll
  for (int kk = 0; kk < 8; ++kk) { vi += ip[j + 32 * kk]; vu += up[j + 32 * kk]; }

  #pragma unroll
  for (int off = 32; off > 0; off >>= 1) bsum += __shfl_down(bsum, off, 64);
  #pragma unroll
  for (int off = 16; off > 0; off >>= 1) {
    vi += __shfl_down(vi, off, 32);
    vu += __shfl_down(vu, off, 32);
  }
  if ((t & 63) == 0) sB[t >> 6] = bsum;
  if (j == 0) { sI[img] = vi; sU[img] = vu; }
  __syncthreads();

  if (t == 0) {
    double bt = 0.0;
    #pragma unroll
    for (int wv = 0; wv < 16; ++wv) bt += (double)sB[wv];
    double bce = bt / ((double)NB * HH * WW);
    double s = 0.0;
    for (int b = 0; b < NB; ++b) {
      double inter = (double)sI[b];
      double uni   = (double)sU[b];
      double wiou  = 1.0 - (inter + 1.0) / (uni - inter + 1.0);
      s += bce + wiou;   // wbce[b,c] == bce exactly (scalar * weit, renormalized)
    }
    out[0] = (float)(s / NB);
  }
}

extern "C" void kernel_launch(void* const* d_in, const int* in_sizes, int n_in,
                              void* d_out, int out_size, void* d_ws, size_t ws_size,
                              hipStream_t stream)
{
  const float* inp = (const float*)d_in[0];
  const float* tgt = (const float*)d_in[1];
  float* ws = (float*)d_ws;   // 3*8192 floats = 96 KB; fully written each launch

  wloss_main<<<NBLK, 256, 0, stream>>>(inp, tgt, ws);
  wloss_final<<<1, 1024, 0, stream>>>(ws, (float*)d_out);
}